// Round 5
// baseline (10955.578 us; speedup 1.0000x reference)
//
#include <hip/hip_runtime.h>
#include <hip/hip_bf16.h>
#include <math.h>

#define NH 8
#define DEPTH 64
#define SEQ 2048
#define BATCH 4
#define DM 512
#define DFFN 2048
#define NROWS (BATCH * SEQ)   // 8192

typedef unsigned short u16;
typedef __attribute__((ext_vector_type(8))) short short8;  // 8 bf16 (4 VGPRs)
typedef __attribute__((ext_vector_type(4))) float f32x4;   // MFMA C/D

__device__ __forceinline__ float bf2f(unsigned short u) {
    union { unsigned int i; float f; } c;
    c.i = ((unsigned int)u) << 16;
    return c.f;
}
__device__ __forceinline__ u16 f2bf(float f) {
    union { float f; unsigned int i; } c; c.f = f;
    unsigned int r = c.i + 0x7fffu + ((c.i >> 16) & 1u);   // RNE
    return (u16)(r >> 16);
}
// dual-dtype input load: f32 ? fp32[i] : bf16[i]
__device__ __forceinline__ float ldin(const void* p, long i, int f32) {
    return f32 ? ((const float*)p)[i] : bf2f(((const unsigned short*)p)[i]);
}

#define GLOAD_LDS16(g, l) __builtin_amdgcn_global_load_lds( \
    (__attribute__((address_space(1))) void*)(g), \
    (__attribute__((address_space(3))) void*)(l), 16, 0, 0)

// ===========================================================================
// ============  Round-2 pipeline, VERBATIM (proven passing)  ================
// ===========================================================================

__global__ void detect_kernel(const void* w, int* flag) {
    if (threadIdx.x == 0 && blockIdx.x == 0) {
        const unsigned short* u = (const unsigned short*)w;
        int isf32 = 0;
        for (int i = 0; i < 2048; ++i) {
            float v = fabsf(bf2f(u[i]));
            if (!(v < 1e3f)) { isf32 = 1; break; }
        }
        *flag = isf32;
    }
}

__global__ void probe_kernel(const int* flag, int* sink) {
    if (*flag) {
        float a = (float)threadIdx.x;
        for (int i = 0; i < 20000; ++i) a = fmaf(a, 1.0000001f, 0.125f);
        if (a == 123.456f) *sink = 1;
    }
}

template<bool A_INPUT, bool GATHER_IN, bool SPLIT_OUT, bool RELU>
__global__ __launch_bounds__(256)
void gemm_kernel(const void* __restrict__ A,
                 const void* __restrict__ W,
                 const void* __restrict__ bias,
                 float* __restrict__ C,
                 int M, int N, int K, const int* __restrict__ dflag)
{
    const int f32 = *dflag;
    __shared__ float As[16][65];
    __shared__ float Bs[16][65];
    const int tx = threadIdx.x, ty = threadIdx.y;
    const int tid = ty * 16 + tx;
    const int bx = blockIdx.x, by = blockIdx.y;

    float acc[4][4] = {};

    for (int kt = 0; kt < K; kt += 16) {
        #pragma unroll
        for (int i = 0; i < 4; ++i) {
            int idx = tid + i * 256;
            int kk  = idx >> 6;
            int mm  = idx & 63;
            int gk  = kt + kk;
            int gm = by * 64 + mm;
            long ai;
            if (GATHER_IN) {
                int b = gm / SEQ, s = gm % SEQ;
                int hh = gk >> 6, dep = gk & 63;
                ai = ((long)(b * NH + hh) * SEQ + s) * DEPTH + dep;
            } else {
                ai = (long)gm * K + gk;
            }
            As[kk][mm] = A_INPUT ? ldin(A, ai, f32) : ((const float*)A)[ai];
            int gn = bx * 64 + mm;
            Bs[kk][mm] = ldin(W, (long)gk * N + gn, f32);
        }
        __syncthreads();

        #pragma unroll
        for (int kk = 0; kk < 16; ++kk) {
            float a[4], b[4];
            #pragma unroll
            for (int i = 0; i < 4; ++i) a[i] = As[kk][ty * 4 + i];
            #pragma unroll
            for (int j = 0; j < 4; ++j) b[j] = Bs[kk][tx * 4 + j];
            #pragma unroll
            for (int i = 0; i < 4; ++i)
                #pragma unroll
                for (int j = 0; j < 4; ++j)
                    acc[i][j] = fmaf(a[i], b[j], acc[i][j]);
        }
        __syncthreads();
    }

    #pragma unroll
    for (int i = 0; i < 4; ++i) {
        int gm = by * 64 + ty * 4 + i;
        #pragma unroll
        for (int j = 0; j < 4; ++j) {
            int gn = bx * 64 + tx * 4 + j;
            float v = acc[i][j] + ldin(bias, gn, f32);
            if (RELU) v = fmaxf(v, 0.f);
            long oi;
            if (SPLIT_OUT) {
                int b = gm / SEQ, s = gm % SEQ;
                int hh = gn >> 6, dep = gn & 63;
                oi = ((long)(b * NH + hh) * SEQ + s) * DEPTH + dep;
            } else {
                oi = (long)gm * N + gn;
            }
            C[oi] = v;
        }
    }
}

__global__ __launch_bounds__(256)
void attn_kernel(const float* __restrict__ q, const float* __restrict__ k,
                 const float* __restrict__ v, float* __restrict__ ctx)
{
    __shared__ float Qs[64][65];
    __shared__ float Ks[64][65];
    __shared__ float Vs[64][65];
    __shared__ float Ps[64][65];
    __shared__ float mrow[64], lrow[64], arow[64];

    const int tx = threadIdx.x, ty = threadIdx.y;
    const int tid = ty * 16 + tx;
    const int bh = blockIdx.y;
    const int q0 = blockIdx.x * 64;

    const float* qh = q + (long)bh * SEQ * DEPTH;
    const float* kh = k + (long)bh * SEQ * DEPTH;
    const float* vh = v + (long)bh * SEQ * DEPTH;

    #pragma unroll
    for (int i = 0; i < 16; ++i) {
        int idx = tid + i * 256;
        int r = idx >> 6, c = idx & 63;
        Qs[r][c] = qh[(long)(q0 + r) * DEPTH + c];
    }
    if (tid < 64) { mrow[tid] = -1e30f; lrow[tid] = 0.f; }

    float o[4][4] = {};
    __syncthreads();

    for (int kt = 0; kt < SEQ; kt += 64) {
        #pragma unroll
        for (int i = 0; i < 16; ++i) {
            int idx = tid + i * 256;
            int r = idx >> 6, c = idx & 63;
            Ks[r][c] = kh[(long)(kt + r) * DEPTH + c];
            Vs[r][c] = vh[(long)(kt + r) * DEPTH + c];
        }
        __syncthreads();

        float sc[4][4] = {};
        #pragma unroll 8
        for (int d = 0; d < 64; ++d) {
            float a[4], b[4];
            #pragma unroll
            for (int i = 0; i < 4; ++i) a[i] = Qs[ty * 4 + i][d];
            #pragma unroll
            for (int j = 0; j < 4; ++j) b[j] = Ks[tx * 4 + j][d];
            #pragma unroll
            for (int i = 0; i < 4; ++i)
                #pragma unroll
                for (int j = 0; j < 4; ++j)
                    sc[i][j] = fmaf(a[i], b[j], sc[i][j]);
        }
        #pragma unroll
        for (int i = 0; i < 4; ++i)
            #pragma unroll
            for (int j = 0; j < 4; ++j)
                Ps[ty * 4 + i][tx * 4 + j] = sc[i][j];
        __syncthreads();

        if (tid < 64) {
            float m = mrow[tid];
            float mn = m;
            #pragma unroll 8
            for (int c = 0; c < 64; ++c) mn = fmaxf(mn, Ps[tid][c]);
            float alpha = __expf(m - mn);
            float sum = 0.f;
            #pragma unroll 8
            for (int c = 0; c < 64; ++c) {
                float p = __expf(Ps[tid][c] - mn);
                Ps[tid][c] = p;
                sum += p;
            }
            mrow[tid] = mn;
            lrow[tid] = lrow[tid] * alpha + sum;
            arow[tid] = alpha;
        }
        __syncthreads();

        #pragma unroll
        for (int i = 0; i < 4; ++i) {
            float al = arow[ty * 4 + i];
            #pragma unroll
            for (int j = 0; j < 4; ++j) o[i][j] *= al;
        }
        #pragma unroll 8
        for (int d = 0; d < 64; ++d) {
            float p[4], vv[4];
            #pragma unroll
            for (int i = 0; i < 4; ++i) p[i] = Ps[ty * 4 + i][d];
            #pragma unroll
            for (int j = 0; j < 4; ++j) vv[j] = Vs[d][tx * 4 + j];
            #pragma unroll
            for (int i = 0; i < 4; ++i)
                #pragma unroll
                for (int j = 0; j < 4; ++j)
                    o[i][j] = fmaf(p[i], vv[j], o[i][j]);
        }
        __syncthreads();
    }

    float* ch = ctx + (long)bh * SEQ * DEPTH;
    #pragma unroll
    for (int i = 0; i < 4; ++i) {
        float inv = 1.f / lrow[ty * 4 + i];
        #pragma unroll
        for (int j = 0; j < 4; ++j)
            ch[(long)(q0 + ty * 4 + i) * DEPTH + tx * 4 + j] = o[i][j] * inv;
    }
}

template<bool A_INPUT, bool FINAL>
__global__ __launch_bounds__(256)
void ln_kernel(const void* __restrict__ a, const float* __restrict__ b,
               const void* __restrict__ g, const void* __restrict__ be,
               void* __restrict__ out, const int* __restrict__ dflag)
{
    const int f32 = *dflag;
    const long row = blockIdx.x;
    const int tid = threadIdx.x;
    const long base = row * DM;

    float v0 = (A_INPUT ? ldin(a, base + tid, f32)       : ((const float*)a)[base + tid])       + b[base + tid];
    float v1 = (A_INPUT ? ldin(a, base + tid + 256, f32) : ((const float*)a)[base + tid + 256]) + b[base + tid + 256];
    float s = v0 + v1;
    float ss = v0 * v0 + v1 * v1;

    #pragma unroll
    for (int off = 32; off > 0; off >>= 1) {
        s  += __shfl_down(s, off);
        ss += __shfl_down(ss, off);
    }
    __shared__ float shs[4], shss[4];
    __shared__ float mean_s, rstd_s;
    const int wid = tid >> 6, lane = tid & 63;
    if (lane == 0) { shs[wid] = s; shss[wid] = ss; }
    __syncthreads();
    if (tid == 0) {
        float S = shs[0] + shs[1] + shs[2] + shs[3];
        float SS = shss[0] + shss[1] + shss[2] + shss[3];
        float mean = S / DM;
        float var = SS / DM - mean * mean;
        mean_s = mean;
        rstd_s = rsqrtf(var + 1e-6f);
    }
    __syncthreads();
    float mean = mean_s, r = rstd_s;

    float o0 = (v0 - mean) * r * ldin(g, tid, f32)       + ldin(be, tid, f32);
    float o1 = (v1 - mean) * r * ldin(g, tid + 256, f32) + ldin(be, tid + 256, f32);
    if (FINAL) {
        if (f32) {
            ((float*)out)[base + tid] = o0;
            ((float*)out)[base + tid + 256] = o1;
        } else {
            ((__hip_bfloat16*)out)[base + tid] = __float2bfloat16(o0);
            ((__hip_bfloat16*)out)[base + tid + 256] = __float2bfloat16(o1);
        }
    } else {
        ((float*)out)[base + tid] = o0;
        ((float*)out)[base + tid + 256] = o1;
    }
}

// ===========================================================================
// =================  Minimal-surface MFMA diagnostics  ======================
// All probes write ONLY counts[] (atomicAdd) — they cannot touch d_out or
// any buffer the proven pipeline reads.
// ===========================================================================

__global__ void zero_kernel(int* p) { p[threadIdx.x] = 0; }

// slot 0: MFMA fragment-layout micro-test (1 wave, pure LDS, no GLL)
__global__ void micro_mfma(const u16* __restrict__ x, int* counts)
{
    __shared__ u16 A[16 * 32], B[32 * 16];
    int l = threadIdx.x;
    for (int i = l; i < 512; i += 64) { A[i] = x[i]; B[i] = x[512 + i]; }
    __syncthreads();
    int m = l & 15, quad = l >> 4;
    short8 af, bf;
    #pragma unroll
    for (int j = 0; j < 8; ++j) {
        af[j] = (short)A[m * 32 + quad * 8 + j];      // A[m][k=quad*8+j]
        bf[j] = (short)B[(quad * 8 + j) * 16 + m];    // B[k][n=m]
    }
    f32x4 d = (f32x4){0.f, 0.f, 0.f, 0.f};
    d = __builtin_amdgcn_mfma_f32_16x16x32_bf16(af, bf, d, 0, 0, 0);
    int bad = 0;
    for (int r = 0; r < 4; ++r) {
        int row = quad * 4 + r;                        // C: col=lane&15, row=quad*4+reg
        float e = 0.f;
        for (int k = 0; k < 32; ++k) e += bf2f(A[row * 32 + k]) * bf2f(B[k * 16 + m]);
        float g = d[r];
        if (g != g || fabsf(g - e) > 0.01f) bad++;
    }
    if (bad) atomicAdd(&counts[0], bad);
}

// slot 1: SWIZZLED global_load_lds micro-test (1 wave, bit-exact)
__global__ void micro_stage(const u16* __restrict__ x, int* counts)
{
    __shared__ __align__(16) u16 L[8 * 64];
    int l = threadIdx.x;
    int rl = l >> 3, cc = l & 7;
    GLOAD_LDS16(x + rl * 64 + ((cc ^ rl) << 3), L);
    __syncthreads();
    int r = l >> 3, s = l & 7;
    int bad = 0;
    for (int j = 0; j < 8; ++j)
        if (L[r * 64 + s * 8 + j] != x[r * 64 + ((s ^ r) << 3) + j]) bad++;
    if (bad) atomicAdd(&counts[1], bad);
}

// slot 2: lP within-wave write->read ordering + swizzle micro-test (1 wave)
__global__ void micro_lp(int* counts)
{
    __shared__ __align__(16) u16 P[16 * 64];
    int l = threadIdx.x;
    int rowb = (l >> 4) * 4;
    for (int u = 0; u < 4; ++u) {
        int c = u * 16 + (l & 15);
        for (int r = 0; r < 4; ++r) {
            int rr = rowb + r;
            P[rr * 64 + ((((c >> 3) ^ (rr & 7)) << 3) | (c & 7))] = (u16)(rr * 64 + c);
        }
    }
    int bad = 0;
    for (int ks = 0; ks < 2; ++ks) {
        int q = ks * 4 + (l >> 4);
        int rp = l & 15;
        short8 pf = *(const short8*)(P + rp * 64 + ((q ^ (rp & 7)) << 3));
        for (int j = 0; j < 8; ++j)
            if ((u16)pf[j] != (u16)(rp * 64 + q * 8 + j)) bad++;
    }
    if (bad) atomicAdd(&counts[2], bad);
}

// slot 3: CONTIGUOUS (m97-style) global_load_lds micro-test (1 wave)
__global__ void micro_plain(const u16* __restrict__ x, int* counts)
{
    __shared__ __align__(16) u16 L[512];
    int l = threadIdx.x;
    GLOAD_LDS16(x + l * 8, L);
    __syncthreads();
    int bad = 0;
    for (int j = 0; j < 8; ++j)
        if (L[l * 8 + j] != x[l * 8 + j]) bad++;
    if (bad) atomicAdd(&counts[3], bad);
}

// The round-3 MFMA GEMM (mode 0 only), for the 128x128x64 toy test.
template<int OUT_MODE, bool RELU, bool SWIZ>
__global__ __launch_bounds__(256)
void mgemm(const u16* __restrict__ A, const u16* __restrict__ BT,
           const u16* __restrict__ bias, void* __restrict__ C,
           int M, int N, int K)
{
    __shared__ __align__(16) u16 lA[128 * 64];
    __shared__ __align__(16) u16 lB[128 * 64];
    const int tid = threadIdx.x;
    const int w = tid >> 6, lane = tid & 63;
    const int wm = w >> 1, wn = w & 1;
    const int rl = lane >> 3, cc = lane & 7;
    const int bm = blockIdx.y, bn = blockIdx.x;
    const long am0 = (long)bm * 128;
    const long bn0 = (long)bn * 128;

    f32x4 acc[4][4];
    #pragma unroll
    for (int t = 0; t < 4; ++t)
        #pragma unroll
        for (int u = 0; u < 4; ++u) acc[t][u] = (f32x4){0.f, 0.f, 0.f, 0.f};

    for (int k0 = 0; k0 < K; k0 += 64) {
        const int sc = SWIZ ? (cc ^ rl) : cc;
        #pragma unroll
        for (int i = 0; i < 4; ++i) {
            int ra = w * 32 + i * 8;
            GLOAD_LDS16(A  + (am0 + ra + rl) * K + k0 + (sc << 3), lA + ra * 64);
            GLOAD_LDS16(BT + (bn0 + ra + rl) * K + k0 + (sc << 3), lB + ra * 64);
        }
        __syncthreads();

        #pragma unroll
        for (int ks = 0; ks < 2; ++ks) {
            const int q = ks * 4 + (lane >> 4);
            short8 af[4], bf[4];
            #pragma unroll
            for (int t = 0; t < 4; ++t) {
                int r = wm * 64 + t * 16 + (lane & 15);
                int sl = SWIZ ? (q ^ (r & 7)) : q;
                af[t] = *(const short8*)(lA + r * 64 + (sl << 3));
            }
            #pragma unroll
            for (int u = 0; u < 4; ++u) {
                int r = wn * 64 + u * 16 + (lane & 15);
                int sl = SWIZ ? (q ^ (r & 7)) : q;
                bf[u] = *(const short8*)(lB + r * 64 + (sl << 3));
            }
            #pragma unroll
            for (int t = 0; t < 4; ++t)
                #pragma unroll
                for (int u = 0; u < 4; ++u)
                    acc[t][u] = __builtin_amdgcn_mfma_f32_16x16x32_bf16(af[t], bf[u], acc[t][u], 0, 0, 0);
        }
        __syncthreads();
    }

    #pragma unroll
    for (int t = 0; t < 4; ++t) {
        #pragma unroll
        for (int u = 0; u < 4; ++u) {
            int n = bn * 128 + wn * 64 + u * 16 + (lane & 15);
            float bv = bf2f(bias[n]);
            #pragma unroll
            for (int r = 0; r < 4; ++r) {
                int m = bm * 128 + wm * 64 + t * 16 + (lane >> 4) * 4 + r;
                float v = acc[t][u][r] + bv;
                if (RELU) v = fmaxf(v, 0.f);
                ((u16*)C)[(long)m * N + n] = f2bf(v);
            }
        }
    }
}

// slot 4: toy mgemm (M=N=128, K=64 from x) vs scalar ref
__global__ void cmp_toy(const u16* __restrict__ x, const u16* __restrict__ Ct,
                        int* counts)
{
    int t = blockIdx.x * 256 + threadIdx.x;   // 16384
    int m = t >> 7, n = t & 127;
    float acc = 0.f;
    for (int k = 0; k < 64; ++k)
        acc += bf2f(x[m * 64 + k]) * bf2f(x[8192 + n * 64 + k]);
    acc += bf2f(x[16384 + n]);
    float got = bf2f(Ct[t]);
    if (got != got || fabsf(got - acc) > 0.08f) atomicAdd(&counts[4], 1);
}

// Duration-coded, DISTINCTLY-NAMED readouts (names survive into rocprof).
__device__ __forceinline__ void spin_body(int fire, int* sink, int iters)
{
    if (!fire) return;
    float a = 1.0f + threadIdx.x * 1e-7f;
    for (int i = 0; i < iters; ++i) a = fmaf(a, 1.0000001f, 1e-9f);
    if (a == -123.0f) *sink = 1;   // never true
}
__global__ void spin_canary(const int* c, int* sink) { spin_body(1,        sink, 1500 * 600); }
__global__ void spin_plain (const int* c, int* sink) { spin_body(c[3] > 0, sink, 1800 * 600); }
__global__ void spin_lp    (const int* c, int* sink) { spin_body(c[2] > 0, sink, 2100 * 600); }
__global__ void spin_stage (const int* c, int* sink) { spin_body(c[1] > 0, sink, 2400 * 600); }
__global__ void spin_mfma  (const int* c, int* sink) { spin_body(c[0] > 0, sink, 2700 * 600); }
__global__ void spin_gemm  (const int* c, int* sink) { spin_body(c[4] > 0, sink, 3000 * 600); }

// ===========================================================================
extern "C" void kernel_launch(void* const* d_in, const int* in_sizes, int n_in,
                              void* d_out, int out_size, void* d_ws, size_t ws_size,
                              hipStream_t stream)
{
    const void* x   = d_in[0];
    const void* Wq  = d_in[1];
    const void* bq  = d_in[2];
    const void* Wk  = d_in[3];
    const void* bk  = d_in[4];
    const void* Wv  = d_in[5];
    const void* bv  = d_in[6];
    const void* Wo  = d_in[7];
    const void* bo  = d_in[8];
    const void* W1  = d_in[9];
    const void* b1  = d_in[10];
    const void* W2  = d_in[11];
    const void* b2  = d_in[12];
    const void* g1  = d_in[13];
    const void* be1 = d_in[14];
    const void* g2  = d_in[15];
    const void* be2 = d_in[16];
    const u16* xb = (const u16*)x;

    const size_t CH = (size_t)NROWS * DM;   // 4,194,304 floats = 16 MiB
    float* qb   = (float*)d_ws;             // [0,16) MiB
    float* kb   = qb + CH;                  // [16,32)
    float* vb   = kb + CH;                  // [32,48)
    float* ctx  = vb + CH;                  // [48,64)
    float* attn = ctx + CH;                 // [64,80)
    float* x1   = attn + CH;                // [80,96)
    float* hbuf = qb;                       // reuse [0,64)
    float* ffb  = attn;                     // reuse [64,80)
    int*   flag = (int*)(qb + 6 * CH);      // at 96 MiB (proven reachable, round 2)
    int*   sinkf = flag + 1;

    // Diagnostic scratch lives inside the attn region [64,80) — it is consumed
    // by the spin kernels BEFORE the pipeline overwrites it.
    char*  ws8   = (char*)d_ws;
    u16*   toyC  = (u16*)(ws8 + 64l * 1024 * 1024);            // 32 KiB
    int*   counts = (int*)(ws8 + 64l * 1024 * 1024 + 65536);   // 16 ints
    int*   sink   = counts + 8;

    // ---- probes first (write only toyC + counts) ----
    zero_kernel<<<1, 16, 0, stream>>>(counts);
    micro_mfma <<<1, 64, 0, stream>>>(xb, counts);
    micro_stage<<<1, 64, 0, stream>>>(xb, counts);
    micro_lp   <<<1, 64, 0, stream>>>(counts);
    micro_plain<<<1, 64, 0, stream>>>(xb, counts);
    mgemm<0, false, true><<<dim3(1, 1), 256, 0, stream>>>(xb, xb + 8192, xb + 16384, toyC, 128, 128, 64);
    cmp_toy<<<64, 256, 0, stream>>>(xb, toyC, counts);
    spin_canary<<<1, 64, 0, stream>>>(counts, sink);
    spin_plain <<<1, 64, 0, stream>>>(counts, sink);
    spin_lp    <<<1, 64, 0, stream>>>(counts, sink);
    spin_stage <<<1, 64, 0, stream>>>(counts, sink);
    spin_mfma  <<<1, 64, 0, stream>>>(counts, sink);
    spin_gemm  <<<1, 64, 0, stream>>>(counts, sink);

    // ---- proven round-2 pipeline, verbatim ----
    dim3 blk(16, 16);

    detect_kernel<<<1, 64, 0, stream>>>(Wq, flag);
    probe_kernel<<<1, 64, 0, stream>>>(flag, sinkf);

    gemm_kernel<true, false, true, false><<<dim3(DM / 64, NROWS / 64), blk, 0, stream>>>(x, Wq, bq, qb, NROWS, DM, DM, flag);
    gemm_kernel<true, false, true, false><<<dim3(DM / 64, NROWS / 64), blk, 0, stream>>>(x, Wk, bk, kb, NROWS, DM, DM, flag);
    gemm_kernel<true, false, true, false><<<dim3(DM / 64, NROWS / 64), blk, 0, stream>>>(x, Wv, bv, vb, NROWS, DM, DM, flag);

    attn_kernel<<<dim3(SEQ / 64, BATCH * NH), blk, 0, stream>>>(qb, kb, vb, ctx);

    gemm_kernel<false, true, false, false><<<dim3(DM / 64, NROWS / 64), blk, 0, stream>>>(ctx, Wo, bo, attn, NROWS, DM, DM, flag);

    ln_kernel<true, false><<<NROWS, 256, 0, stream>>>(x, attn, g1, be1, x1, flag);

    gemm_kernel<false, false, false, true><<<dim3(DFFN / 64, NROWS / 64), blk, 0, stream>>>(x1, W1, b1, hbuf, NROWS, DFFN, DM, flag);

    gemm_kernel<false, false, false, false><<<dim3(DM / 64, NROWS / 64), blk, 0, stream>>>(hbuf, W2, b2, ffb, NROWS, DM, DFFN, flag);

    ln_kernel<false, true><<<NROWS, 256, 0, stream>>>(x1, ffb, g2, be2, d_out, flag);
}